// Round 1
// baseline (35593.408 us; speedup 1.0000x reference)
//
#include <hip/hip_runtime.h>
#include <hip/hip_fp16.h>

#define BATCH 64
#define TSEQ  2048
#define FEAT  256
#define HID   256
#define G4    1024   // 4*HID

typedef _Float16 half2_t __attribute__((ext_vector_type(2)));

__device__ __forceinline__ float dot2acc(float a, float b, float acc) {
    half2_t ah = __builtin_bit_cast(half2_t, a);
    half2_t bh = __builtin_bit_cast(half2_t, b);
#if __has_builtin(__builtin_amdgcn_fdot2)
    return __builtin_amdgcn_fdot2(ah, bh, acc, false);
#else
    return acc + (float)ah.x * (float)bh.x + (float)ah.y * (float)bh.y;
#endif
}

__device__ __forceinline__ float sig_f(float x) {
    return 1.f / (1.f + __expf(-x));
}
// tanh(x) = 1 - 2/(exp(2x)+1): safe for |x| large (exp->inf => 1; exp->0 => -1)
__device__ __forceinline__ float tanh_f(float x) {
    return 1.f - 2.f / (__expf(2.f * x) + 1.f);
}

// ---------------- prep: WeightH fp32 [k][j] -> fp16 transposed [j][k] ----------------
__global__ void wt_convert(const float* __restrict__ WH, _Float16* __restrict__ WT) {
    int idx = blockIdx.x * 256 + threadIdx.x;   // 262144 total
    int j = idx >> 8;     // 0..1023 (gate column)
    int k = idx & 255;    // 0..255
    WT[idx] = (_Float16)WH[k * G4 + j];
}

// ---------------- phase 1: xp = x @ Wx + bx + bh, stored fp16 ----------------
// M = BATCH*TSEQ = 131072, K = 256, N = 1024. 64x64 tile, 256 threads, 4x4/thread.
__global__ __launch_bounds__(256) void xproj_gemm(
    const float* __restrict__ X, const float* __restrict__ WX,
    const float* __restrict__ BX, const float* __restrict__ BH,
    _Float16* __restrict__ XP)
{
    __shared__ float As[64][17];   // +1 pad: ty-groups land on distinct banks
    __shared__ float Bs[16][68];   // +4 pad: keeps rows 16B-aligned, 2-way max (free)

    const int tid = threadIdx.x;
    const int tx = tid & 15;     // n-dir
    const int ty = tid >> 4;     // m-dir
    const int rowBase = blockIdx.y * 64;
    const int colBase = blockIdx.x * 64;

    // staging indices (4 contiguous elements per thread)
    const int ea = tid * 4;
    const int ar = ea >> 4, ac = ea & 15;   // As[ar][ac..ac+3]
    const int br = ea >> 6, bc = ea & 63;   // Bs[br][bc..bc+3]

    float acc[4][4] = {};

    for (int kt = 0; kt < FEAT; kt += 16) {
        float4 av = *(const float4*)(X  + (size_t)(rowBase + ar) * FEAT + kt + ac);
        float4 bv = *(const float4*)(WX + (size_t)(kt + br) * G4 + colBase + bc);
        As[ar][ac + 0] = av.x; As[ar][ac + 1] = av.y;
        As[ar][ac + 2] = av.z; As[ar][ac + 3] = av.w;
        *(float4*)&Bs[br][bc] = bv;
        __syncthreads();
        #pragma unroll
        for (int kk = 0; kk < 16; ++kk) {
            float4 b = *(const float4*)&Bs[kk][tx * 4];
            float a0 = As[ty * 4 + 0][kk];
            float a1 = As[ty * 4 + 1][kk];
            float a2 = As[ty * 4 + 2][kk];
            float a3 = As[ty * 4 + 3][kk];
            acc[0][0] = fmaf(a0, b.x, acc[0][0]); acc[0][1] = fmaf(a0, b.y, acc[0][1]);
            acc[0][2] = fmaf(a0, b.z, acc[0][2]); acc[0][3] = fmaf(a0, b.w, acc[0][3]);
            acc[1][0] = fmaf(a1, b.x, acc[1][0]); acc[1][1] = fmaf(a1, b.y, acc[1][1]);
            acc[1][2] = fmaf(a1, b.z, acc[1][2]); acc[1][3] = fmaf(a1, b.w, acc[1][3]);
            acc[2][0] = fmaf(a2, b.x, acc[2][0]); acc[2][1] = fmaf(a2, b.y, acc[2][1]);
            acc[2][2] = fmaf(a2, b.z, acc[2][2]); acc[2][3] = fmaf(a2, b.w, acc[2][3]);
            acc[3][0] = fmaf(a3, b.x, acc[3][0]); acc[3][1] = fmaf(a3, b.y, acc[3][1]);
            acc[3][2] = fmaf(a3, b.z, acc[3][2]); acc[3][3] = fmaf(a3, b.w, acc[3][3]);
        }
        __syncthreads();
    }

    const int n0 = colBase + tx * 4;
    float4 bxv = *(const float4*)(BX + n0);
    float4 bhv = *(const float4*)(BH + n0);
    float bb0 = bxv.x + bhv.x, bb1 = bxv.y + bhv.y;
    float bb2 = bxv.z + bhv.z, bb3 = bxv.w + bhv.w;

    #pragma unroll
    for (int i = 0; i < 4; ++i) {
        int row = rowBase + ty * 4 + i;
        _Float16* p = XP + (size_t)row * G4 + n0;
        half2_t p01 = { (_Float16)(acc[i][0] + bb0), (_Float16)(acc[i][1] + bb1) };
        half2_t p23 = { (_Float16)(acc[i][2] + bb2), (_Float16)(acc[i][3] + bb3) };
        *(half2_t*)(p + 0) = p01;
        *(half2_t*)(p + 2) = p23;
    }
}

// ---------------- phase 2: sequential recurrence, one block per batch element ----------------
// 1024 threads: thread j computes gate column j each step (fp16 dot2, fp32 acc).
// Threads 0..255 own c[j] in a register and do the elementwise update.
__global__ __launch_bounds__(1024) void lstm_rec(
    const _Float16* __restrict__ XP, const _Float16* __restrict__ WT,
    float* __restrict__ OUT)
{
    __shared__ __align__(16) _Float16 h_sh[HID];
    __shared__ float g_sh[G4];

    const int b = blockIdx.x;
    const int j = threadIdx.x;

    if (j < HID) h_sh[j] = (_Float16)0.f;
    float c = 0.f;

    const float4* wrow = (const float4*)(WT + (size_t)j * HID);  // 32 float4 = 256 fp16
    const _Float16* xpb = XP + (size_t)b * TSEQ * G4;
    float* outb = OUT + (size_t)b * TSEQ * HID;
    __syncthreads();

    for (int t = 0; t < TSEQ; ++t) {
        float xv = (float)xpb[(size_t)t * G4 + j];   // issued early, used after k-loop
        float acc = 0.f;
        const float4* h4 = (const float4*)h_sh;
        #pragma unroll 8
        for (int kk = 0; kk < 32; ++kk) {
            float4 hv = h4[kk];      // ds_read_b128: 8 h values per LDS instr
            float4 wv = wrow[kk];    // 16B global load, L2-resident stream
            acc = dot2acc(hv.x, wv.x, acc);
            acc = dot2acc(hv.y, wv.y, acc);
            acc = dot2acc(hv.z, wv.z, acc);
            acc = dot2acc(hv.w, wv.w, acc);
        }
        g_sh[j] = acc + xv;
        __syncthreads();

        if (j < HID) {
            float gi = sig_f(g_sh[j]);
            float gf = sig_f(g_sh[j + HID]);
            float gg = tanh_f(g_sh[j + 2 * HID]);
            float go = sig_f(g_sh[j + 3 * HID]);
            c = gf * c + gi * gg;
            float h = go * tanh_f(c);
            outb[(size_t)t * HID + j] = h;
            h_sh[j] = (_Float16)h;
            if (t == TSEQ - 1) {
                OUT[(size_t)BATCH * TSEQ * HID + (size_t)b * HID + j] = h;
            }
        }
        __syncthreads();
    }
}

extern "C" void kernel_launch(void* const* d_in, const int* in_sizes, int n_in,
                              void* d_out, int out_size, void* d_ws, size_t ws_size,
                              hipStream_t stream) {
    const float* x  = (const float*)d_in[0];
    const float* wx = (const float*)d_in[1];
    const float* wh = (const float*)d_in[2];
    const float* bx = (const float*)d_in[3];
    const float* bh = (const float*)d_in[4];
    float* out = (float*)d_out;

    // workspace layout: [xp fp16: 64*2048*1024] [WT fp16: 1024*256]
    _Float16* xp = (_Float16*)d_ws;
    _Float16* wt = (_Float16*)((char*)d_ws + (size_t)BATCH * TSEQ * G4 * sizeof(_Float16));

    hipLaunchKernelGGL(wt_convert, dim3(1024), dim3(256), 0, stream, wh, wt);
    hipLaunchKernelGGL(xproj_gemm, dim3(G4 / 64, (BATCH * TSEQ) / 64), dim3(256), 0, stream,
                       x, wx, bx, bh, xp);
    hipLaunchKernelGGL(lstm_rec, dim3(BATCH), dim3(1024), 0, stream, xp, wt, out);
}

// Round 2
// 10860.159 us; speedup vs baseline: 3.2774x; 3.2774x over previous
//
#include <hip/hip_runtime.h>
#include <hip/hip_fp16.h>

#define BATCH 64
#define TSEQ  2048
#define FEAT  256
#define HID   256
#define G4    1024   // 4*HID

typedef _Float16 half2_t __attribute__((ext_vector_type(2)));

__device__ __forceinline__ float dot2acc_u(unsigned int a, unsigned int b, float acc) {
    half2_t ah = __builtin_bit_cast(half2_t, a);
    half2_t bh = __builtin_bit_cast(half2_t, b);
#if __has_builtin(__builtin_amdgcn_fdot2)
    return __builtin_amdgcn_fdot2(ah, bh, acc, false);
#else
    return acc + (float)ah.x * (float)bh.x + (float)ah.y * (float)bh.y;
#endif
}

__device__ __forceinline__ float sig_f(float x)  { return 1.f / (1.f + __expf(-x)); }
// tanh(x) = 1 - 2/(exp(2x)+1): safe for |x| large
__device__ __forceinline__ float tanh_f(float x) { return 1.f - 2.f / (__expf(2.f * x) + 1.f); }

__device__ __forceinline__ unsigned int pack2(float a, float b) {
    half2_t h = { (_Float16)a, (_Float16)b };
    return __builtin_bit_cast(unsigned int, h);
}

// ---------------- prep: WeightH fp32 [k][j] -> packed-half2, chunked layout ----------------
// WT4 layout: uint4 WT4[32][1024]; WT4[c][j] holds k-range [8c, 8c+8) of column j,
// packed as 4x half2 (low half = even k). Lane-consecutive j => consecutive 16 B (coalesced).
__global__ void wt_convert(const float* __restrict__ WH, uint4* __restrict__ WT4) {
    int idx = blockIdx.x * 256 + threadIdx.x;   // 32768 total
    int c = idx >> 10;      // 0..31 k-chunk
    int j = idx & 1023;     // column
    int k0 = c * 8;
    uint4 v;
    v.x = pack2(WH[(k0 + 0) * G4 + j], WH[(k0 + 1) * G4 + j]);
    v.y = pack2(WH[(k0 + 2) * G4 + j], WH[(k0 + 3) * G4 + j]);
    v.z = pack2(WH[(k0 + 4) * G4 + j], WH[(k0 + 5) * G4 + j]);
    v.w = pack2(WH[(k0 + 6) * G4 + j], WH[(k0 + 7) * G4 + j]);
    WT4[idx] = v;
}

// ---------------- phase 1: xp = x @ Wx + bx + bh, stored fp16 ----------------
__global__ __launch_bounds__(256) void xproj_gemm(
    const float* __restrict__ X, const float* __restrict__ WX,
    const float* __restrict__ BX, const float* __restrict__ BH,
    _Float16* __restrict__ XP)
{
    __shared__ float As[64][17];
    __shared__ float Bs[16][68];

    const int tid = threadIdx.x;
    const int tx = tid & 15;
    const int ty = tid >> 4;
    const int rowBase = blockIdx.y * 64;
    const int colBase = blockIdx.x * 64;

    const int ea = tid * 4;
    const int ar = ea >> 4, ac = ea & 15;
    const int br = ea >> 6, bc = ea & 63;

    float acc[4][4] = {};

    for (int kt = 0; kt < FEAT; kt += 16) {
        float4 av = *(const float4*)(X  + (size_t)(rowBase + ar) * FEAT + kt + ac);
        float4 bv = *(const float4*)(WX + (size_t)(kt + br) * G4 + colBase + bc);
        As[ar][ac + 0] = av.x; As[ar][ac + 1] = av.y;
        As[ar][ac + 2] = av.z; As[ar][ac + 3] = av.w;
        *(float4*)&Bs[br][bc] = bv;
        __syncthreads();
        #pragma unroll
        for (int kk = 0; kk < 16; ++kk) {
            float4 b = *(const float4*)&Bs[kk][tx * 4];
            float a0 = As[ty * 4 + 0][kk];
            float a1 = As[ty * 4 + 1][kk];
            float a2 = As[ty * 4 + 2][kk];
            float a3 = As[ty * 4 + 3][kk];
            acc[0][0] = fmaf(a0, b.x, acc[0][0]); acc[0][1] = fmaf(a0, b.y, acc[0][1]);
            acc[0][2] = fmaf(a0, b.z, acc[0][2]); acc[0][3] = fmaf(a0, b.w, acc[0][3]);
            acc[1][0] = fmaf(a1, b.x, acc[1][0]); acc[1][1] = fmaf(a1, b.y, acc[1][1]);
            acc[1][2] = fmaf(a1, b.z, acc[1][2]); acc[1][3] = fmaf(a1, b.w, acc[1][3]);
            acc[2][0] = fmaf(a2, b.x, acc[2][0]); acc[2][1] = fmaf(a2, b.y, acc[2][1]);
            acc[2][2] = fmaf(a2, b.z, acc[2][2]); acc[2][3] = fmaf(a2, b.w, acc[2][3]);
            acc[3][0] = fmaf(a3, b.x, acc[3][0]); acc[3][1] = fmaf(a3, b.y, acc[3][1]);
            acc[3][2] = fmaf(a3, b.z, acc[3][2]); acc[3][3] = fmaf(a3, b.w, acc[3][3]);
        }
        __syncthreads();
    }

    const int n0 = colBase + tx * 4;
    float4 bxv = *(const float4*)(BX + n0);
    float4 bhv = *(const float4*)(BH + n0);
    float bb0 = bxv.x + bhv.x, bb1 = bxv.y + bhv.y;
    float bb2 = bxv.z + bhv.z, bb3 = bxv.w + bhv.w;

    #pragma unroll
    for (int i = 0; i < 4; ++i) {
        int row = rowBase + ty * 4 + i;
        _Float16* p = XP + (size_t)row * G4 + n0;
        half2_t p01 = { (_Float16)(acc[i][0] + bb0), (_Float16)(acc[i][1] + bb1) };
        half2_t p23 = { (_Float16)(acc[i][2] + bb2), (_Float16)(acc[i][3] + bb3) };
        *(half2_t*)(p + 0) = p01;
        *(half2_t*)(p + 2) = p23;
    }
}

// ---------------- phase 2: recurrence, one block per batch, weights in registers ----------------
// Thread j owns gate column j. Its 256 fp16 weights live in w[32] (uint4 = 8 fp16) = 128 VGPRs,
// loaded ONCE before the t-loop (coalesced: lane-consecutive j -> consecutive 16 B).
// h is read via wave-uniform ds_read_b128 (hardware broadcast, conflict-free).
__global__ __launch_bounds__(1024) void lstm_rec(
    const _Float16* __restrict__ XP, const uint4* __restrict__ WT4,
    float* __restrict__ OUT)
{
    __shared__ __align__(16) _Float16 h_sh[HID];
    __shared__ float g_sh[G4];

    const int b = blockIdx.x;
    const int j = threadIdx.x;

    // ---- one-time weight preload into registers ----
    uint4 w[32];
    #pragma unroll
    for (int c = 0; c < 32; ++c) w[c] = WT4[c * G4 + j];

    if (j < HID) h_sh[j] = (_Float16)0.f;
    float cst = 0.f;
    float hlast = 0.f;
    float h_hist[8];

    const _Float16* xpb = XP + (size_t)b * TSEQ * G4;
    float* outb = OUT + (size_t)b * TSEQ * HID;
    __syncthreads();

    #pragma unroll 1
    for (int t = 0; t < TSEQ; ++t) {
        float xv = (float)xpb[(size_t)t * G4 + j];   // issued early; used after k-loop
        float acc = 0.f;
        const uint4* h4 = (const uint4*)h_sh;        // 16 uint4 = 256 fp16... (32B each? no: 16B)
        #pragma unroll
        for (int kk = 0; kk < 32; ++kk) {
            uint4 hv = h4[kk];                       // wave-uniform broadcast ds_read_b128
            acc = dot2acc_u(hv.x, w[kk].x, acc);
            acc = dot2acc_u(hv.y, w[kk].y, acc);
            acc = dot2acc_u(hv.z, w[kk].z, acc);
            acc = dot2acc_u(hv.w, w[kk].w, acc);
        }
        g_sh[j] = acc + xv;
        __syncthreads();

        if (j < HID) {
            float gi = sig_f(g_sh[j]);
            float gf = sig_f(g_sh[j + HID]);
            float gg = tanh_f(g_sh[j + 2 * HID]);
            float go = sig_f(g_sh[j + 3 * HID]);
            cst = gf * cst + gi * gg;
            float h = go * tanh_f(cst);
            h_sh[j] = (_Float16)h;
            hlast = h;
            h_hist[t & 7] = h;
            if ((t & 7) == 7) {       // flush 8 rows at once: one vmcnt drain per 8 steps
                #pragma unroll
                for (int r = 0; r < 8; ++r)
                    outb[(size_t)(t - 7 + r) * HID + j] = h_hist[r];
            }
        }
        __syncthreads();
    }

    if (j < HID) {
        OUT[(size_t)BATCH * TSEQ * HID + (size_t)b * HID + j] = hlast;
    }
}

extern "C" void kernel_launch(void* const* d_in, const int* in_sizes, int n_in,
                              void* d_out, int out_size, void* d_ws, size_t ws_size,
                              hipStream_t stream) {
    const float* x  = (const float*)d_in[0];
    const float* wx = (const float*)d_in[1];
    const float* wh = (const float*)d_in[2];
    const float* bx = (const float*)d_in[3];
    const float* bh = (const float*)d_in[4];
    float* out = (float*)d_out;

    // workspace: [xp fp16: 64*2048*1024] [WT4: 32*1024 uint4 = 512 KB]
    _Float16* xp = (_Float16*)d_ws;
    uint4* wt4 = (uint4*)((char*)d_ws + (size_t)BATCH * TSEQ * G4 * sizeof(_Float16));

    hipLaunchKernelGGL(wt_convert, dim3(128), dim3(256), 0, stream, wh, wt4);
    hipLaunchKernelGGL(xproj_gemm, dim3(G4 / 64, (BATCH * TSEQ) / 64), dim3(256), 0, stream,
                       x, wx, bx, bh, xp);
    hipLaunchKernelGGL(lstm_rec, dim3(BATCH), dim3(1024), 0, stream, xp, wt4, out);
}

// Round 4
// 5640.327 us; speedup vs baseline: 6.3105x; 1.9254x over previous
//
#include <hip/hip_runtime.h>
#include <hip/hip_fp16.h>

#define BATCH 64
#define TSEQ  2048
#define FEAT  256
#define HID   256
#define G4    1024   // 4*HID

typedef _Float16 half2_t __attribute__((ext_vector_type(2)));

__device__ __forceinline__ float dot2acc_u(unsigned int a, unsigned int b, float acc) {
    half2_t ah = __builtin_bit_cast(half2_t, a);
    half2_t bh = __builtin_bit_cast(half2_t, b);
#if __has_builtin(__builtin_amdgcn_fdot2)
    return __builtin_amdgcn_fdot2(ah, bh, acc, false);
#else
    return acc + (float)ah.x * (float)bh.x + (float)ah.y * (float)bh.y;
#endif
}

__device__ __forceinline__ float sig_f(float x)  { return 1.f / (1.f + __expf(-x)); }
__device__ __forceinline__ float tanh_f(float x) { return 1.f - 2.f / (__expf(2.f * x) + 1.f); }

__device__ __forceinline__ unsigned int pack2(float a, float b) {
    half2_t h = { (_Float16)a, (_Float16)b };
    return __builtin_bit_cast(unsigned int, h);
}

// DPP cross-lane add: x += lane-shuffled(x). CTRL must be a compile-time constant
// (Sema checks before inlining -> template parameter). 0xB1=quad_perm[1,0,3,2] (xor1),
// 0x4E=quad_perm[2,3,0,1] (xor2), 0x141=row_half_mirror (xor4 within 8-lane groups).
template <int CTRL>
__device__ __forceinline__ float dpp_add(float x) {
    int y = __builtin_amdgcn_update_dpp(0, __builtin_bit_cast(int, x), CTRL, 0xf, 0xf, true);
    return x + __builtin_bit_cast(float, y);
}

// ---------------- prep: WeightH fp32 [k][j] -> k-split swizzled fp16 ----------------
// Thread (p,w,c,s) computes gate col j = p*64 + w*8 + c, k-slice s: k in [32s, 32s+32).
// uint4 u covers k in [32s+8u, 32s+8u+8) packed as 4x half2 (k-ascending).
// WS[u*8192 + p*512 + tid] for passes p=0..12 (persist + LDS).
// WST[(q*4+u)*512 + tid] (+6144 replica) for streamed passes p=13+q; 2 copies so the
// per-step loads are loop-VARIANT ((t&1) base) and can't be LICM-hoisted into registers.
__global__ void wt_convert(const float* __restrict__ WH, uint4* __restrict__ WS,
                           uint4* __restrict__ WST) {
    int idx = blockIdx.x * 256 + threadIdx.x;   // 32768 total
    int u = idx >> 13;          // 0..3
    int r = idx & 8191;
    int p = r >> 9;             // 0..15
    int tid = r & 511;
    int w = tid >> 6, c = (tid >> 3) & 7, s = tid & 7;
    int j = p * 64 + w * 8 + c;
    int k0 = 32 * s + 8 * u;
    uint4 v;
    v.x = pack2(WH[(k0 + 0) * G4 + j], WH[(k0 + 1) * G4 + j]);
    v.y = pack2(WH[(k0 + 2) * G4 + j], WH[(k0 + 3) * G4 + j]);
    v.z = pack2(WH[(k0 + 4) * G4 + j], WH[(k0 + 5) * G4 + j]);
    v.w = pack2(WH[(k0 + 6) * G4 + j], WH[(k0 + 7) * G4 + j]);
    if (p < 13) {
        WS[u * 8192 + p * 512 + tid] = v;
    } else {
        int q = p - 13;
        WST[(q * 4 + u) * 512 + tid] = v;
        WST[6144 + (q * 4 + u) * 512 + tid] = v;
    }
}

// ---------------- phase 1: xp = x @ Wx + bx + bh, stored fp16 (unchanged) ----------------
__global__ __launch_bounds__(256) void xproj_gemm(
    const float* __restrict__ X, const float* __restrict__ WX,
    const float* __restrict__ BX, const float* __restrict__ BH,
    _Float16* __restrict__ XP)
{
    __shared__ float As[64][17];
    __shared__ float Bs[16][68];

    const int tid = threadIdx.x;
    const int tx = tid & 15;
    const int ty = tid >> 4;
    const int rowBase = blockIdx.y * 64;
    const int colBase = blockIdx.x * 64;

    const int ea = tid * 4;
    const int ar = ea >> 4, ac = ea & 15;
    const int br = ea >> 6, bc = ea & 63;

    float acc[4][4] = {};

    for (int kt = 0; kt < FEAT; kt += 16) {
        float4 av = *(const float4*)(X  + (size_t)(rowBase + ar) * FEAT + kt + ac);
        float4 bv = *(const float4*)(WX + (size_t)(kt + br) * G4 + colBase + bc);
        As[ar][ac + 0] = av.x; As[ar][ac + 1] = av.y;
        As[ar][ac + 2] = av.z; As[ar][ac + 3] = av.w;
        *(float4*)&Bs[br][bc] = bv;
        __syncthreads();
        #pragma unroll
        for (int kk = 0; kk < 16; ++kk) {
            float4 b = *(const float4*)&Bs[kk][tx * 4];
            float a0 = As[ty * 4 + 0][kk];
            float a1 = As[ty * 4 + 1][kk];
            float a2 = As[ty * 4 + 2][kk];
            float a3 = As[ty * 4 + 3][kk];
            acc[0][0] = fmaf(a0, b.x, acc[0][0]); acc[0][1] = fmaf(a0, b.y, acc[0][1]);
            acc[0][2] = fmaf(a0, b.z, acc[0][2]); acc[0][3] = fmaf(a0, b.w, acc[0][3]);
            acc[1][0] = fmaf(a1, b.x, acc[1][0]); acc[1][1] = fmaf(a1, b.y, acc[1][1]);
            acc[1][2] = fmaf(a1, b.z, acc[1][2]); acc[1][3] = fmaf(a1, b.w, acc[1][3]);
            acc[2][0] = fmaf(a2, b.x, acc[2][0]); acc[2][1] = fmaf(a2, b.y, acc[2][1]);
            acc[2][2] = fmaf(a2, b.z, acc[2][2]); acc[2][3] = fmaf(a2, b.w, acc[2][3]);
            acc[3][0] = fmaf(a3, b.x, acc[3][0]); acc[3][1] = fmaf(a3, b.y, acc[3][1]);
            acc[3][2] = fmaf(a3, b.z, acc[3][2]); acc[3][3] = fmaf(a3, b.w, acc[3][3]);
        }
        __syncthreads();
    }

    const int n0 = colBase + tx * 4;
    float4 bxv = *(const float4*)(BX + n0);
    float4 bhv = *(const float4*)(BH + n0);
    float bb0 = bxv.x + bhv.x, bb1 = bxv.y + bhv.y;
    float bb2 = bxv.z + bhv.z, bb3 = bxv.w + bhv.w;

    #pragma unroll
    for (int i = 0; i < 4; ++i) {
        int row = rowBase + ty * 4 + i;
        _Float16* p = XP + (size_t)row * G4 + n0;
        half2_t p01 = { (_Float16)(acc[i][0] + bb0), (_Float16)(acc[i][1] + bb1) };
        half2_t p23 = { (_Float16)(acc[i][2] + bb2), (_Float16)(acc[i][3] + bb3) };
        *(half2_t*)(p + 0) = p01;
        *(half2_t*)(p + 2) = p23;
    }
}

// ---------------- phase 2: recurrence, k-split dot + DPP reduce ----------------
// 512 threads (8 waves), 1 batch/block. Thread (w,c,s): 16 passes, pass p computes
// gate col j = p*64 + w*8 + c, over its k-slice [32s,32s+32). Weights: passes 0-11
// persist in VGPRs (48 uint4 = 192 regs), pass 12 in LDS, passes 13-15 streamed
// from L2 each step (96 KB/step, parity-replicated base to defeat LICM).
// h: each lane reads only its 64 B slice (4 ds_read_b128/thread/step, broadcast-free).
#define DO_PASS(P, W0, W1, W2, W3)                                              \
    {                                                                           \
        float acc = 0.f;                                                        \
        acc = dot2acc_u(hr0.x, (W0).x, acc); acc = dot2acc_u(hr0.y, (W0).y, acc); \
        acc = dot2acc_u(hr0.z, (W0).z, acc); acc = dot2acc_u(hr0.w, (W0).w, acc); \
        acc = dot2acc_u(hr1.x, (W1).x, acc); acc = dot2acc_u(hr1.y, (W1).y, acc); \
        acc = dot2acc_u(hr1.z, (W1).z, acc); acc = dot2acc_u(hr1.w, (W1).w, acc); \
        acc = dot2acc_u(hr2.x, (W2).x, acc); acc = dot2acc_u(hr2.y, (W2).y, acc); \
        acc = dot2acc_u(hr2.z, (W2).z, acc); acc = dot2acc_u(hr2.w, (W2).w, acc); \
        acc = dot2acc_u(hr3.x, (W3).x, acc); acc = dot2acc_u(hr3.y, (W3).y, acc); \
        acc = dot2acc_u(hr3.z, (W3).z, acc); acc = dot2acc_u(hr3.w, (W3).w, acc); \
        acc = dpp_add<0xB1>(acc);                                               \
        acc = dpp_add<0x4E>(acc);                                               \
        acc = dpp_add<0x141>(acc);                                              \
        if (s == 0) g_sh[(P) * 64 + w * 8 + c] = acc;                           \
    }

__global__ __launch_bounds__(512, 2) void lstm_rec(
    const _Float16* __restrict__ XP, const uint4* __restrict__ WS,
    const uint4* __restrict__ WST, float* __restrict__ OUT)
{
    __shared__ uint4 LDS_W[4 * 512];                      // pass 12 weights, 32 KB
    __shared__ float g_sh[G4];                            // 4 KB
    __shared__ __align__(16) unsigned short hs[4][64];    // hs[u][s*8+e] = h[32s+8u+e]

    const int tid = threadIdx.x;
    const int b = blockIdx.x;
    const int w = tid >> 6;
    const int c = (tid >> 3) & 7;
    const int s = tid & 7;

    // one-time: persist weights (passes 0-11) into registers
    uint4 wreg[48];
    #pragma unroll
    for (int p = 0; p < 12; ++p) {
        #pragma unroll
        for (int u = 0; u < 4; ++u)
            wreg[p * 4 + u] = WS[u * 8192 + p * 512 + tid];
    }
    // one-time: pass 12 into LDS (SoA, conflict-free 16 B stride)
    #pragma unroll
    for (int u = 0; u < 4; ++u)
        LDS_W[u * 512 + tid] = WS[u * 8192 + 12 * 512 + tid];

    if (tid < 256) ((unsigned short*)hs)[tid] = 0;
    float cst = 0.f, hlast = 0.f;
    const _Float16* xpb = XP + (size_t)b * TSEQ * G4;
    float* outb = OUT + (size_t)b * TSEQ * HID;
    __syncthreads();

    #pragma unroll 1
    for (int t = 0; t < TSEQ; ++t) {
        // h slice for this lane: 64 B in 4x b128 (reused across all 16 passes)
        uint4 hr0 = ((const uint4*)(&hs[0][0]))[s];
        uint4 hr1 = ((const uint4*)(&hs[1][0]))[s];
        uint4 hr2 = ((const uint4*)(&hs[2][0]))[s];
        uint4 hr3 = ((const uint4*)(&hs[3][0]))[s];

        // xp for the elementwise phase — issue early
        float xv0 = 0.f, xv1 = 0.f, xv2 = 0.f, xv3 = 0.f;
        if (tid < 256) {
            const _Float16* xq = xpb + (size_t)t * G4;
            xv0 = (float)xq[tid];       xv1 = (float)xq[tid + 256];
            xv2 = (float)xq[tid + 512]; xv3 = (float)xq[tid + 768];
        }

        const uint4* stb = WST + (size_t)(t & 1) * 6144;  // parity replica: loop-variant
        uint4 pf0 = stb[(0 * 4 + 0) * 512 + tid];
        uint4 pf1 = stb[(0 * 4 + 1) * 512 + tid];
        uint4 pf2 = stb[(0 * 4 + 2) * 512 + tid];
        uint4 pf3 = stb[(0 * 4 + 3) * 512 + tid];

        DO_PASS(0,  wreg[0],  wreg[1],  wreg[2],  wreg[3]);
        DO_PASS(1,  wreg[4],  wreg[5],  wreg[6],  wreg[7]);
        DO_PASS(2,  wreg[8],  wreg[9],  wreg[10], wreg[11]);
        DO_PASS(3,  wreg[12], wreg[13], wreg[14], wreg[15]);
        DO_PASS(4,  wreg[16], wreg[17], wreg[18], wreg[19]);
        DO_PASS(5,  wreg[20], wreg[21], wreg[22], wreg[23]);

        DO_PASS(13, pf0, pf1, pf2, pf3);                  // consume stream pass 13
        pf0 = stb[(1 * 4 + 0) * 512 + tid];               // issue pass 14
        pf1 = stb[(1 * 4 + 1) * 512 + tid];
        pf2 = stb[(1 * 4 + 2) * 512 + tid];
        pf3 = stb[(1 * 4 + 3) * 512 + tid];

        DO_PASS(6,  wreg[24], wreg[25], wreg[26], wreg[27]);
        DO_PASS(7,  wreg[28], wreg[29], wreg[30], wreg[31]);
        DO_PASS(8,  wreg[32], wreg[33], wreg[34], wreg[35]);
        DO_PASS(9,  wreg[36], wreg[37], wreg[38], wreg[39]);
        DO_PASS(10, wreg[40], wreg[41], wreg[42], wreg[43]);
        DO_PASS(11, wreg[44], wreg[45], wreg[46], wreg[47]);

        DO_PASS(14, pf0, pf1, pf2, pf3);                  // consume pass 14
        pf0 = stb[(2 * 4 + 0) * 512 + tid];               // issue pass 15
        pf1 = stb[(2 * 4 + 1) * 512 + tid];
        pf2 = stb[(2 * 4 + 2) * 512 + tid];
        pf3 = stb[(2 * 4 + 3) * 512 + tid];

        {   // pass 12 from LDS
            uint4 l0 = LDS_W[0 * 512 + tid];
            uint4 l1 = LDS_W[1 * 512 + tid];
            uint4 l2 = LDS_W[2 * 512 + tid];
            uint4 l3 = LDS_W[3 * 512 + tid];
            DO_PASS(12, l0, l1, l2, l3);
        }
        DO_PASS(15, pf0, pf1, pf2, pf3);                  // consume pass 15

        __syncthreads();

        if (tid < 256) {
            float gi = sig_f(g_sh[tid] + xv0);
            float gf = sig_f(g_sh[tid + 256] + xv1);
            float gg = tanh_f(g_sh[tid + 512] + xv2);
            float go = sig_f(g_sh[tid + 768] + xv3);
            cst = gf * cst + gi * gg;
            float h = go * tanh_f(cst);
            outb[(size_t)t * HID + tid] = h;
            hlast = h;
            hs[(tid >> 3) & 3][(tid >> 5) * 8 + (tid & 7)] =
                __builtin_bit_cast(unsigned short, (_Float16)h);
        }
        __syncthreads();
    }

    if (tid < 256)
        OUT[(size_t)BATCH * TSEQ * HID + (size_t)b * HID + tid] = hlast;
}

extern "C" void kernel_launch(void* const* d_in, const int* in_sizes, int n_in,
                              void* d_out, int out_size, void* d_ws, size_t ws_size,
                              hipStream_t stream) {
    const float* x  = (const float*)d_in[0];
    const float* wx = (const float*)d_in[1];
    const float* wh = (const float*)d_in[2];
    const float* bx = (const float*)d_in[3];
    const float* bh = (const float*)d_in[4];
    float* out = (float*)d_out;

    // workspace: [xp fp16: 256 MB][WS: 32768 uint4 = 512 KB][WST: 12288 uint4 = 192 KB]
    _Float16* xp = (_Float16*)d_ws;
    uint4* ws = (uint4*)((char*)d_ws + (size_t)BATCH * TSEQ * G4 * sizeof(_Float16));
    uint4* wst = ws + 32768;

    hipLaunchKernelGGL(wt_convert, dim3(128), dim3(256), 0, stream, wh, ws, wst);
    hipLaunchKernelGGL(xproj_gemm, dim3(G4 / 64, (BATCH * TSEQ) / 64), dim3(256), 0, stream,
                       x, wx, bx, bh, xp);
    hipLaunchKernelGGL(lstm_rec, dim3(BATCH), dim3(512), 0, stream, xp, ws, wst, out);
}